// Round 1
// baseline (240.035 us; speedup 1.0000x reference)
//
#include <hip/hip_runtime.h>

// Problem constants
#define B 16
#define C 64
#define SS 4096      // H*W
#define TT 1024      // S/4 (pooled keys)
#define CQ 8         // C/8  (theta/phi channels)
#define CG 32        // C/2  (g channels)

#define TS 64        // s-rows per block in attention kernel
#define TC 64        // t-chunk width
#define NCHUNK (TT / TC)

// ---------------------------------------------------------------------------
// K1: theta[b][o][s] = sum_c w_theta[o][c] * x[b][c][s]
// ---------------------------------------------------------------------------
__global__ __launch_bounds__(256) void proj_theta_kernel(
        const float* __restrict__ x, const float* __restrict__ w_theta,
        float* __restrict__ theta) {
    __shared__ float w[CQ * C];
    int tid = threadIdx.x;
    for (int i = tid; i < CQ * C; i += 256) w[i] = w_theta[i];
    __syncthreads();

    int gid = blockIdx.x * 256 + tid;       // over B*S
    int b = gid >> 12;
    int s = gid & (SS - 1);
    const float* xb = x + (size_t)b * C * SS + s;

    float acc[CQ];
#pragma unroll
    for (int o = 0; o < CQ; ++o) acc[o] = 0.f;
    for (int c = 0; c < C; ++c) {
        float xv = xb[(size_t)c * SS];
#pragma unroll
        for (int o = 0; o < CQ; ++o) acc[o] += w[o * C + c] * xv;
    }
    float* tb = theta + (size_t)b * CQ * SS + s;
#pragma unroll
    for (int o = 0; o < CQ; ++o) tb[(size_t)o * SS] = acc[o];
}

// ---------------------------------------------------------------------------
// K2: phi[b][o][t] = maxpool2x2(w_phi . x),  g[b][c][t] = maxpool2x2(w_g . x)
// ---------------------------------------------------------------------------
__global__ __launch_bounds__(256) void proj_pool_kernel(
        const float* __restrict__ x, const float* __restrict__ w_phi,
        const float* __restrict__ w_g, float* __restrict__ phi,
        float* __restrict__ g) {
    __shared__ float wp[CQ * C];
    __shared__ float wg[CG * C];
    int tid = threadIdx.x;
    for (int i = tid; i < CQ * C; i += 256) wp[i] = w_phi[i];
    for (int i = tid; i < CG * C; i += 256) wg[i] = w_g[i];
    __syncthreads();

    int gid = blockIdx.x * 256 + tid;       // over B*T
    int b = gid >> 10;
    int t = gid & (TT - 1);
    int ph = t >> 5, pw = t & 31;
    const float* xb = x + (size_t)b * C * SS;

    float bphi[CQ], bg[CG];
#pragma unroll
    for (int o = 0; o < CQ; ++o) bphi[o] = -1e30f;
#pragma unroll
    for (int o = 0; o < CG; ++o) bg[o] = -1e30f;

#pragma unroll
    for (int pos = 0; pos < 4; ++pos) {
        int h = 2 * ph + (pos >> 1);
        int w_ = 2 * pw + (pos & 1);
        int s = h * 64 + w_;
        float ap[CQ], ag[CG];
#pragma unroll
        for (int o = 0; o < CQ; ++o) ap[o] = 0.f;
#pragma unroll
        for (int o = 0; o < CG; ++o) ag[o] = 0.f;
        for (int c = 0; c < C; ++c) {
            float xv = xb[(size_t)c * SS + s];
#pragma unroll
            for (int o = 0; o < CQ; ++o) ap[o] += wp[o * C + c] * xv;
#pragma unroll
            for (int o = 0; o < CG; ++o) ag[o] += wg[o * C + c] * xv;
        }
#pragma unroll
        for (int o = 0; o < CQ; ++o) bphi[o] = fmaxf(bphi[o], ap[o]);
#pragma unroll
        for (int o = 0; o < CG; ++o) bg[o] = fmaxf(bg[o], ag[o]);
    }
    float* pb = phi + (size_t)b * CQ * TT + t;
    float* gb = g + (size_t)b * CG * TT + t;
#pragma unroll
    for (int o = 0; o < CQ; ++o) pb[(size_t)o * TT] = bphi[o];
#pragma unroll
    for (int o = 0; o < CG; ++o) gb[(size_t)o * TT] = bg[o];
}

// ---------------------------------------------------------------------------
// K3: fused flash-style attention + w_o epilogue + residual
//   block -> (b, s-tile of TS rows). Online softmax over t chunks.
// ---------------------------------------------------------------------------
__global__ __launch_bounds__(256) void attn_kernel(
        const float* __restrict__ x, const float* __restrict__ theta,
        const float* __restrict__ phi, const float* __restrict__ g,
        const float* __restrict__ w_o, const float* __restrict__ gamma_p,
        float* __restrict__ out) {
    __shared__ float th_s[CQ][TS];          // 2 KB
    __shared__ float phi_s[CQ][TC];         // 2 KB
    __shared__ float g_s[CG][TC];           // 8 KB
    __shared__ float p_s[TS][TC + 1];       // 16.25 KB
    __shared__ float wo_s[C * CG];          // 8 KB
    __shared__ float attn_s[CG][TS + 1];    // 8.125 KB
    __shared__ float m_s[TS], l_s[TS], scale_s[TS];
    __shared__ float red_s[TS][4];

    int tid = threadIdx.x;
    int b = blockIdx.x >> 6;                // 64 s-tiles per batch
    int s0 = (blockIdx.x & 63) * TS;

    for (int i = tid; i < C * CG; i += 256) wo_s[i] = w_o[i];
    for (int i = tid; i < CQ * TS; i += 256) {
        int o = i >> 6, si = i & 63;
        th_s[o][si] = theta[(size_t)b * CQ * SS + (size_t)o * SS + s0 + si];
    }
    if (tid < TS) { m_s[tid] = -1e30f; l_s[tid] = 0.f; }
    __syncthreads();

    // accumulator mapping: cg = tid>>5 (8 groups of 4 c), sg = tid&31 (2 s each)
    int cg = tid >> 5, sg = tid & 31;
    int c0 = cg * 4;
    int ss0 = sg * 2;
    float acc[4][2];
#pragma unroll
    for (int i = 0; i < 4; ++i)
        for (int j = 0; j < 2; ++j) acc[i][j] = 0.f;

    const float* phib = phi + (size_t)b * CQ * TT;
    const float* gb = g + (size_t)b * CG * TT;

    // score-compute mapping: row r = tid&63, t-quarter q = tid>>6
    int r = tid & 63, q = tid >> 6;

    for (int tc = 0; tc < NCHUNK; ++tc) {
        int tbase = tc * TC;
        // stage phi/g chunks
        for (int i = tid; i < CQ * TC; i += 256) {
            int o = i >> 6, ti = i & 63;
            phi_s[o][ti] = phib[(size_t)o * TT + tbase + ti];
        }
        for (int i = tid; i < CG * TC; i += 256) {
            int o = i >> 6, ti = i & 63;
            g_s[o][ti] = gb[(size_t)o * TT + tbase + ti];
        }
        __syncthreads();

        // scores for (r, t = q*16 .. q*16+15)
        float tr[CQ];
#pragma unroll
        for (int o = 0; o < CQ; ++o) tr[o] = th_s[o][r];
#pragma unroll
        for (int ti = 0; ti < TC / 4; ++ti) {
            int t = q * (TC / 4) + ti;
            float sc = 0.f;
#pragma unroll
            for (int o = 0; o < CQ; ++o) sc += tr[o] * phi_s[o][t];
            p_s[r][t] = sc;
        }
        __syncthreads();

        // chunk max: thread (r2 = tid>>2, j = tid&3) scans 16 entries
        {
            int r2 = tid >> 2, j = tid & 3;
            float pm = -1e30f;
#pragma unroll
            for (int ti = 0; ti < TC / 4; ++ti)
                pm = fmaxf(pm, p_s[r2][j * (TC / 4) + ti]);
            red_s[r2][j] = pm;
        }
        __syncthreads();
        if (tid < TS) {
            float cm = fmaxf(fmaxf(red_s[tid][0], red_s[tid][1]),
                             fmaxf(red_s[tid][2], red_s[tid][3]));
            float om = m_s[tid];
            float nm = fmaxf(om, cm);
            m_s[tid] = nm;
            scale_s[tid] = __expf(om - nm);
        }
        __syncthreads();

        // exp in place + partial row sums
        {
            int r2 = tid >> 2, j = tid & 3;
            float mm = m_s[r2];
            float psum = 0.f;
#pragma unroll
            for (int ti = 0; ti < TC / 4; ++ti) {
                int t = j * (TC / 4) + ti;
                float e = __expf(p_s[r2][t] - mm);
                p_s[r2][t] = e;
                psum += e;
            }
            red_s[r2][j] = psum;
        }
        __syncthreads();
        if (tid < TS) {
            l_s[tid] = l_s[tid] * scale_s[tid] +
                       red_s[tid][0] + red_s[tid][1] + red_s[tid][2] + red_s[tid][3];
        }

        // rescale accumulators for this thread's two s-columns
        float sc0 = scale_s[ss0], sc1 = scale_s[ss0 + 1];
#pragma unroll
        for (int i = 0; i < 4; ++i) { acc[i][0] *= sc0; acc[i][1] *= sc1; }

        // attn accumulation: acc[c][s] += g[c][t] * p[s][t]
        for (int t = 0; t < TC; ++t) {
            float g0 = g_s[c0 + 0][t], g1 = g_s[c0 + 1][t];
            float g2 = g_s[c0 + 2][t], g3 = g_s[c0 + 3][t];
            float p0 = p_s[ss0][t], p1 = p_s[ss0 + 1][t];
            acc[0][0] += g0 * p0; acc[0][1] += g0 * p1;
            acc[1][0] += g1 * p0; acc[1][1] += g1 * p1;
            acc[2][0] += g2 * p0; acc[2][1] += g2 * p1;
            acc[3][0] += g3 * p0; acc[3][1] += g3 * p1;
        }
        __syncthreads();
    }

    // finalize attn tile into LDS
    float il0 = 1.f / l_s[ss0], il1 = 1.f / l_s[ss0 + 1];
#pragma unroll
    for (int i = 0; i < 4; ++i) {
        attn_s[c0 + i][ss0] = acc[i][0] * il0;
        attn_s[c0 + i][ss0 + 1] = acc[i][1] * il1;
    }
    __syncthreads();

    // epilogue: out[b][ch][s0+s] = gamma * (w_o . attn) + x
    {
        int s = tid & 63;
        int ch0 = (tid >> 6) * 16;
        float gm = *gamma_p;
        const float* xb = x + (size_t)b * C * SS + s0 + s;
        float* ob = out + (size_t)b * C * SS + s0 + s;
        for (int chi = 0; chi < 16; ++chi) {
            int ch = ch0 + chi;
            float o = 0.f;
#pragma unroll
            for (int c2 = 0; c2 < CG; ++c2)
                o += wo_s[ch * CG + c2] * attn_s[c2][s];
            ob[(size_t)ch * SS] = gm * o + xb[(size_t)ch * SS];
        }
    }
}

// ---------------------------------------------------------------------------
extern "C" void kernel_launch(void* const* d_in, const int* in_sizes, int n_in,
                              void* d_out, int out_size, void* d_ws, size_t ws_size,
                              hipStream_t stream) {
    const float* x       = (const float*)d_in[0];
    const float* w_theta = (const float*)d_in[1];
    const float* w_phi   = (const float*)d_in[2];
    const float* w_g     = (const float*)d_in[3];
    const float* w_o     = (const float*)d_in[4];
    const float* gamma   = (const float*)d_in[5];
    float* out = (float*)d_out;

    float* ws    = (float*)d_ws;
    float* theta = ws;                              // B*CQ*S  = 524288 floats
    float* phi   = theta + (size_t)B * CQ * SS;     // B*CQ*T  = 131072 floats
    float* g     = phi + (size_t)B * CQ * TT;       // B*CG*T  = 524288 floats

    proj_theta_kernel<<<(B * SS) / 256, 256, 0, stream>>>(x, w_theta, theta);
    proj_pool_kernel<<<(B * TT) / 256, 256, 0, stream>>>(x, w_phi, w_g, phi, g);
    attn_kernel<<<B * (SS / TS), 256, 0, stream>>>(x, theta, phi, g, w_o, gamma, out);
}

// Round 2
// 85.210 us; speedup vs baseline: 2.8170x; 2.8170x over previous
//
#include <hip/hip_runtime.h>

#define B 16
#define C 64
#define SS 4096      // H*W
#define TT 1024      // pooled keys
#define CQ 8         // C/8
#define CG 32        // C/2
#define TC 64        // t-chunk
#define NCH (TT / TC)

typedef _Float16 h4 __attribute__((ext_vector_type(4)));
typedef float f4v __attribute__((ext_vector_type(4)));

#define MFMA16(a, b, c) __builtin_amdgcn_mfma_f32_16x16x16f16((a), (b), (c), 0, 0, 0)

// ---------------------------------------------------------------------------
// K1: theta_t[b][s][o] = (w_theta . x)  stored f16, o-contiguous (16B rows)
// ---------------------------------------------------------------------------
__global__ __launch_bounds__(256) void k_theta(
        const float* __restrict__ x, const float* __restrict__ w_theta,
        _Float16* __restrict__ theta_t) {
    __shared__ float w[CQ * C];
    int tid = threadIdx.x;
    for (int i = tid; i < CQ * C; i += 256) w[i] = w_theta[i];
    __syncthreads();

    int gid = blockIdx.x * 256 + tid;        // over B*SS
    int b = gid >> 12, s = gid & (SS - 1);
    const float* xb = x + (((size_t)b * C) << 12) + s;

    float acc[CQ];
#pragma unroll
    for (int o = 0; o < CQ; ++o) acc[o] = 0.f;
    for (int c = 0; c < C; ++c) {
        float xv = xb[(size_t)c << 12];
#pragma unroll
        for (int o = 0; o < CQ; ++o) acc[o] += w[o * C + c] * xv;
    }
    union { _Float16 h[8]; float4 f; } u;
#pragma unroll
    for (int o = 0; o < CQ; ++o) u.h[o] = (_Float16)acc[o];
    *(float4*)&theta_t[(size_t)gid * 8] = u.f;
}

// ---------------------------------------------------------------------------
// K2: phi_t[b][t][o] (f16, o-contiguous) and g_h[b][c][t] (f16), both
// maxpool2x2 of the channel projections. 4 lane-groups split the 40 channels.
// ---------------------------------------------------------------------------
__global__ __launch_bounds__(256) void k_pool(
        const float* __restrict__ x, const float* __restrict__ w_phi,
        const float* __restrict__ w_g, _Float16* __restrict__ phi_t,
        _Float16* __restrict__ g_h) {
    __shared__ float wall[(CQ + CG) * C];    // rows 0..7 phi, 8..39 g
    int tid = threadIdx.x;
    for (int i = tid; i < CQ * C; i += 256) wall[i] = w_phi[i];
    for (int i = tid; i < CG * C; i += 256) wall[CQ * C + i] = w_g[i];
    __syncthreads();

    int tq = tid & 63, grp = tid >> 6;
    int gid = blockIdx.x * 64 + tq;          // over B*TT
    int b = gid >> 10, t = gid & (TT - 1);
    int ph = t >> 5, pw = t & 31;
    const float* xb = x + (((size_t)b * C) << 12);
    int ch0 = grp * 10;

    float best[10];
#pragma unroll
    for (int i = 0; i < 10; ++i) best[i] = -1e30f;

#pragma unroll
    for (int pos = 0; pos < 4; ++pos) {
        int s = (2 * ph + (pos >> 1)) * 64 + 2 * pw + (pos & 1);
        float a[10];
#pragma unroll
        for (int i = 0; i < 10; ++i) a[i] = 0.f;
        for (int c = 0; c < C; ++c) {
            float xv = xb[((size_t)c << 12) + s];
#pragma unroll
            for (int i = 0; i < 10; ++i) a[i] += wall[(ch0 + i) * C + c] * xv;
        }
#pragma unroll
        for (int i = 0; i < 10; ++i) best[i] = fmaxf(best[i], a[i]);
    }
#pragma unroll
    for (int i = 0; i < 10; ++i) {
        int ch = ch0 + i;
        if (ch < CQ)
            phi_t[((size_t)((b << 10) | t)) * 8 + ch] = (_Float16)best[i];
        else
            g_h[(((size_t)(b * CG + (ch - CQ))) << 10) + t] = (_Float16)best[i];
    }
}

// ---------------------------------------------------------------------------
// K3: MFMA flash attention + mfma w_o epilogue + residual.
// Block = (b, 64 query rows). 4 waves, wave w owns rows sw..sw+16.
// ---------------------------------------------------------------------------
__global__ __launch_bounds__(256) void k_attn(
        const float* __restrict__ x, const _Float16* __restrict__ theta_t,
        const _Float16* __restrict__ phi_t, const _Float16* __restrict__ g_h,
        const float* __restrict__ w_o, const float* __restrict__ gamma_p,
        float* __restrict__ out) {
    __shared__ __align__(16) _Float16 g_sh[CG][72];      // 4.5 KB, 16B-blk XOR swizzle
    __shared__ __align__(16) _Float16 phi_sh[TC][8];     // 1 KB
    __shared__ __align__(16) _Float16 p_sh[4][16][68];   // per-wave P, col XOR swizzle
    __shared__ __align__(16) _Float16 at_sh[4][16][36];  // per-wave attn [s][c]
    __shared__ float sc_sh[4][16];
    __shared__ float l_sh[4][16];

    int tid = threadIdx.x;
    int w = tid >> 6, l = tid & 63;
    int lw = l & 15, lg = l >> 4;            // col / k-group within wave
    int b = blockIdx.x >> 6;
    int s0 = (blockIdx.x & 63) * 64;
    int sw = s0 + w * 16;

    f4v z4 = {0.f, 0.f, 0.f, 0.f};

    // Scores A fragment (theta): lane rows s=sw+lw, k=o=4*lg+e (real k<8)
    h4 a_th;
#pragma unroll
    for (int i = 0; i < 4; ++i) a_th[i] = (_Float16)0;
    if (l < 32)
        a_th = *(const h4*)&theta_t[((size_t)((b << 12) + sw + lw)) * 8 + 4 * lg];

    // Epilogue A fragments (w_o cast to f16): ch = m0*16+lw, k = c = 4*lg+e+16*kk
    h4 a3[4][2];
#pragma unroll
    for (int m0 = 0; m0 < 4; ++m0)
#pragma unroll
        for (int kk = 0; kk < 2; ++kk) {
            float4 wv = *(const float4*)&w_o[(m0 * 16 + lw) * CG + 4 * lg + 16 * kk];
            a3[m0][kk][0] = (_Float16)wv.x;
            a3[m0][kk][1] = (_Float16)wv.y;
            a3[m0][kk][2] = (_Float16)wv.z;
            a3[m0][kk][3] = (_Float16)wv.w;
        }

    float m_r[4], l_r[4];
#pragma unroll
    for (int r = 0; r < 4; ++r) { m_r[r] = -1e30f; l_r[r] = 0.f; }
    f4v acc2[2];
    acc2[0] = z4; acc2[1] = z4;

    const _Float16* gb = g_h + (((size_t)b * CG) << 10);
    const _Float16* pb = phi_t + ((size_t)(b << 10)) * 8;

    for (int tc = 0; tc < NCH; ++tc) {
        int tbase = tc * TC;
        __syncthreads();
        // ---- stage g (32x64 f16) and phi (64x8 f16) ----
        {
            int c = tid >> 3, j = tid & 7;
            *(float4*)&g_sh[c][(j ^ (c & 7)) << 3] =
                *(const float4*)&gb[((size_t)c << 10) + tbase + j * 8];
            if (tid < 64)
                *(float4*)&phi_sh[tid][0] = *(const float4*)&pb[(size_t)(tbase + tid) * 8];
        }
        __syncthreads();

        // ---- scores: D[s][t] = theta^T phi, 4 n0 tiles of 16 t ----
        f4v sc[4];
#pragma unroll
        for (int n0 = 0; n0 < 4; ++n0) {
            h4 bf;
#pragma unroll
            for (int i = 0; i < 4; ++i) bf[i] = (_Float16)0;
            if (l < 32) bf = *(const h4*)&phi_sh[n0 * 16 + lw][4 * lg];
            sc[n0] = MFMA16(a_th, bf, z4);
        }

        // ---- online softmax (rows live across 16-lane groups) ----
        float scl[4];
#pragma unroll
        for (int r = 0; r < 4; ++r) {
            float v = fmaxf(fmaxf(sc[0][r], sc[1][r]), fmaxf(sc[2][r], sc[3][r]));
            v = fmaxf(v, __shfl_xor(v, 1));
            v = fmaxf(v, __shfl_xor(v, 2));
            v = fmaxf(v, __shfl_xor(v, 4));
            v = fmaxf(v, __shfl_xor(v, 8));
            float nm = fmaxf(m_r[r], v);
            scl[r] = __expf(m_r[r] - nm);
            m_r[r] = nm;
        }
        float sum[4];
#pragma unroll
        for (int r = 0; r < 4; ++r) sum[r] = 0.f;
#pragma unroll
        for (int n0 = 0; n0 < 4; ++n0)
#pragma unroll
            for (int r = 0; r < 4; ++r) {
                float p = __expf(sc[n0][r] - m_r[r]);
                sc[n0][r] = p;
                sum[r] += p;
            }
#pragma unroll
        for (int r = 0; r < 4; ++r) {
            float v = sum[r];
            v += __shfl_xor(v, 1);
            v += __shfl_xor(v, 2);
            v += __shfl_xor(v, 4);
            v += __shfl_xor(v, 8);
            l_r[r] = l_r[r] * scl[r] + v;
        }

        // ---- P -> LDS f16 (col XOR-swizzled by row&3) ----
#pragma unroll
        for (int n0 = 0; n0 < 4; ++n0)
#pragma unroll
            for (int r = 0; r < 4; ++r) {
                int row = lg * 4 + r;
                int t = n0 * 16 + lw;
                p_sh[w][row][t ^ ((row & 3) << 3)] = (_Float16)sc[n0][r];
            }
        // scale broadcast row-layout -> col-layout
        if (lw == 0) {
#pragma unroll
            for (int r = 0; r < 4; ++r) sc_sh[w][lg * 4 + r] = scl[r];
        }
        __syncthreads();
        float cscl = sc_sh[w][lw];
        acc2[0] = acc2[0] * cscl;
        acc2[1] = acc2[1] * cscl;

        // ---- PV: attn[c][s] += g[c][t] P[s][t], K=64 in 4 mfma steps ----
#pragma unroll
        for (int kk = 0; kk < 4; ++kk) {
            int t0 = 4 * lg + 16 * kk;
            h4 bp = *(const h4*)&p_sh[w][lw][t0 ^ ((lw & 3) << 3)];
            int jb = (lg >> 1) + 2 * kk;
            int off = ((jb ^ (lw & 7)) << 3) + 4 * (lg & 1);
            h4 ga0 = *(const h4*)&g_sh[lw][off];
            h4 ga1 = *(const h4*)&g_sh[16 + lw][off];
            acc2[0] = MFMA16(ga0, bp, acc2[0]);
            acc2[1] = MFMA16(ga1, bp, acc2[1]);
        }
    }

    // ---- finalize: divide by l, bounce attn to LDS as f16 [s][c] ----
    if (lw == 0) {
#pragma unroll
        for (int r = 0; r < 4; ++r) l_sh[w][lg * 4 + r] = l_r[r];
    }
    __syncthreads();
    float linv = 1.f / l_sh[w][lw];
#pragma unroll
    for (int m0 = 0; m0 < 2; ++m0)
#pragma unroll
        for (int r = 0; r < 4; ++r)
            at_sh[w][lw][m0 * 16 + lg * 4 + r] = (_Float16)(acc2[m0][r] * linv);
    __syncthreads();

    // ---- epilogue: out = gamma * (w_o . attn) + x via mfma ----
    h4 b3[2];
#pragma unroll
    for (int kk = 0; kk < 2; ++kk)
        b3[kk] = *(const h4*)&at_sh[w][lw][4 * lg + 16 * kk];
    float gm = gamma_p[0];
#pragma unroll
    for (int m0 = 0; m0 < 4; ++m0) {
        f4v d = MFMA16(a3[m0][0], b3[0], z4);
        d = MFMA16(a3[m0][1], b3[1], d);
#pragma unroll
        for (int r = 0; r < 4; ++r) {
            int ch = m0 * 16 + lg * 4 + r;
            size_t idx = (((size_t)(b * C + ch)) << 12) + sw + lw;
            out[idx] = gm * d[r] + x[idx];
        }
    }
}

// ---------------------------------------------------------------------------
extern "C" void kernel_launch(void* const* d_in, const int* in_sizes, int n_in,
                              void* d_out, int out_size, void* d_ws, size_t ws_size,
                              hipStream_t stream) {
    const float* x       = (const float*)d_in[0];
    const float* w_theta = (const float*)d_in[1];
    const float* w_phi   = (const float*)d_in[2];
    const float* w_g     = (const float*)d_in[3];
    const float* w_o     = (const float*)d_in[4];
    const float* gamma   = (const float*)d_in[5];
    float* out = (float*)d_out;

    _Float16* ws      = (_Float16*)d_ws;
    _Float16* theta_t = ws;                        // B*SS*8  = 524288 halfs
    _Float16* phi_t   = theta_t + (size_t)B * SS * 8;   // B*TT*8  = 131072
    _Float16* g_h     = phi_t + (size_t)B * TT * 8;     // B*CG*TT = 524288

    k_theta<<<(B * SS) / 256, 256, 0, stream>>>(x, w_theta, theta_t);
    k_pool<<<(B * TT) / 64, 256, 0, stream>>>(x, w_phi, w_g, phi_t, g_h);
    k_attn<<<B * (SS / 64), 256, 0, stream>>>(x, theta_t, phi_t, g_h, w_o, gamma, out);
}

// Round 3
// 76.124 us; speedup vs baseline: 3.1532x; 1.1194x over previous
//
#include <hip/hip_runtime.h>

#define B 16
#define C 64
#define SS 4096      // H*W
#define TT 1024      // pooled keys
#define CQ 8         // C/8
#define CG 32        // C/2

typedef _Float16 h4 __attribute__((ext_vector_type(4)));
typedef float f32x16 __attribute__((ext_vector_type(16)));

#if __has_builtin(__builtin_amdgcn_exp2f)
#define EXP2(x) __builtin_amdgcn_exp2f(x)
#else
#define EXP2(x) exp2f(x)
#endif

#define MFMA328(a, b, c) __builtin_amdgcn_mfma_f32_32x32x8f16((a), (b), (c), 0, 0, 0)

// ---------------------------------------------------------------------------
// KP: one pass over x. Computes:
//   theta_t[b][s][o]  f16, scaled by log2(e)          (o-contiguous, 16B rows)
//   phi_t[b][t][o]    f16                              (o-contiguous)
//   g_blk[b][t>>2][c][t&3] f16  (blocked so KA staging reads are contiguous)
// Lane mapping: 4 consecutive threads = one 2x2 pool quad (t), pos = gid&3.
// ---------------------------------------------------------------------------
__global__ __launch_bounds__(256) void k_proj(
        const float* __restrict__ x, const float* __restrict__ w_theta,
        const float* __restrict__ w_phi, const float* __restrict__ w_g,
        _Float16* __restrict__ theta_t, _Float16* __restrict__ phi_t,
        _Float16* __restrict__ g_blk) {
    int tid = threadIdx.x;
    int gid = blockIdx.x * 256 + tid;        // over B*SS
    int b = gid >> 12;
    int q = (gid >> 2) & 1023;               // t index (pool quad)
    int pos = gid & 3;
    int ph = q >> 5, pw = q & 31;
    int s = (2 * ph + (pos >> 1)) * 64 + 2 * pw + (pos & 1);
    const float* xb = x + ((size_t)b << 18) + s;

    float th[CQ], fp[CQ], fg[CG];
#pragma unroll
    for (int o = 0; o < CQ; ++o) { th[o] = 0.f; fp[o] = 0.f; }
#pragma unroll
    for (int o = 0; o < CG; ++o) fg[o] = 0.f;

#pragma unroll 4
    for (int c = 0; c < C; ++c) {
        float xv = xb[(size_t)c << 12];
#pragma unroll
        for (int o = 0; o < CQ; ++o) th[o] += w_theta[o * C + c] * xv;
#pragma unroll
        for (int o = 0; o < CQ; ++o) fp[o] += w_phi[o * C + c] * xv;
#pragma unroll
        for (int o = 0; o < CG; ++o) fg[o] += w_g[o * C + c] * xv;
    }

    const float LOG2E = 1.44269504088896f;
    union { _Float16 h[8]; float4 f4; } u;
#pragma unroll
    for (int o = 0; o < CQ; ++o) u.h[o] = (_Float16)(th[o] * LOG2E);
    *(float4*)&theta_t[(size_t)((b << 12) + s) * 8] = u.f4;

    // 2x2 max-pool across the quad's 4 lanes
#pragma unroll
    for (int o = 0; o < CQ; ++o) {
        fp[o] = fmaxf(fp[o], __shfl_xor(fp[o], 1));
        fp[o] = fmaxf(fp[o], __shfl_xor(fp[o], 2));
    }
#pragma unroll
    for (int o = 0; o < CG; ++o) {
        fg[o] = fmaxf(fg[o], __shfl_xor(fg[o], 1));
        fg[o] = fmaxf(fg[o], __shfl_xor(fg[o], 2));
    }
    if (pos == 0) {
        union { _Float16 h[8]; float4 f4; } v;
#pragma unroll
        for (int o = 0; o < CQ; ++o) v.h[o] = (_Float16)fp[o];
        *(float4*)&phi_t[(size_t)((b << 10) + q) * 8] = v.f4;
        _Float16* gb = g_blk + (size_t)(b * 256 + (q >> 2)) * 128 + (q & 3);
#pragma unroll
        for (int c2 = 0; c2 < CG; ++c2) gb[c2 * 4] = (_Float16)fg[c2];
    }
}

// ---------------------------------------------------------------------------
// KA: flash attention, swapped-operand 32x32x8 MFMA, P entirely in registers.
// Block = (b, 128 query rows), 4 waves x 32 rows. g for the whole batch is
// staged once in LDS (64 KB, XOR-swizzled 8B blocks); zero barriers in loop.
// ---------------------------------------------------------------------------
__global__ __launch_bounds__(256) void k_attn(
        const float* __restrict__ x, const _Float16* __restrict__ theta_t,
        const _Float16* __restrict__ phi_t, const _Float16* __restrict__ g_blk,
        const float* __restrict__ w_o, const float* __restrict__ gamma_p,
        float* __restrict__ out) {
    __shared__ _Float16 g_sh[CG * TT];       // 64 KB

    int tid = threadIdx.x;
    int bid = blockIdx.x;
    int wg = (bid & 7) * 64 + (bid >> 3);    // XCD-contiguous batches (512%8==0)
    int b = wg >> 5;
    int s0 = (wg & 31) * 128;
    int l = tid & 63;
    int ln = l & 31, hi = l >> 5;
    int sw = s0 + (tid >> 6) * 32;

    // ---- stage g (whole batch): thread (c = tid&31, jg = tid>>5) ----
    {
        int cst = tid & 31, jg = tid >> 5;
        const _Float16* gsrc = g_blk + (size_t)b * (256 * 128) + (size_t)cst * 4;
        _Float16* grow = g_sh + cst * TT;
#pragma unroll 4
        for (int i = 0; i < 32; ++i) {
            int j = jg + 8 * i;
            int js = (j & ~15) | ((j ^ cst) & 15);
            *(h4*)&grow[js * 4] = *(const h4*)&gsrc[(size_t)j * 128];
        }
    }

    // theta B-fragment (col s = sw+ln, k = o = 4*hi+i), loop-invariant
    h4 bth = *(const h4*)&theta_t[(size_t)((b << 12) + sw + ln) * 8 + 4 * hi];

    // w_o A-fragments: ch = mt*32+ln, k = c = 8*kk + 4*hi + i
    h4 a3[2][4];
#pragma unroll
    for (int mt = 0; mt < 2; ++mt)
#pragma unroll
        for (int kk = 0; kk < 4; ++kk) {
            float4 wv = *(const float4*)&w_o[(mt * 32 + ln) * CG + 8 * kk + 4 * hi];
            a3[mt][kk][0] = (_Float16)wv.x;
            a3[mt][kk][1] = (_Float16)wv.y;
            a3[mt][kk][2] = (_Float16)wv.z;
            a3[mt][kk][3] = (_Float16)wv.w;
        }

    const _Float16* phib = phi_t + ((size_t)b << 10) * 8;
    h4 aphi = *(const h4*)&phib[(size_t)ln * 8 + 4 * hi];

    __syncthreads();

    f32x16 zero;
#pragma unroll
    for (int r = 0; r < 16; ++r) zero[r] = 0.f;
    f32x16 acc = zero;
    float m2 = -1e30f, lsum = 0.f;

    for (int tc = 0; tc < TT / 32; ++tc) {
        int tbase = tc * 32;
        h4 acur = aphi;
        if (tc < TT / 32 - 1)
            aphi = *(const h4*)&phib[(size_t)(tbase + 32 + ln) * 8 + 4 * hi];

        // scores D[t][s], t local 0..31, s = sw+ln (lane-fixed)
        f32x16 sc = MFMA328(acur, bth, zero);

        // chunk max for this lane's s (16 regs + partner lane^32)
        float x0 = fmaxf(sc[0], sc[1]),  x1 = fmaxf(sc[2], sc[3]);
        float x2 = fmaxf(sc[4], sc[5]),  x3 = fmaxf(sc[6], sc[7]);
        float x4 = fmaxf(sc[8], sc[9]),  x5 = fmaxf(sc[10], sc[11]);
        float x6 = fmaxf(sc[12], sc[13]), x7 = fmaxf(sc[14], sc[15]);
        x0 = fmaxf(x0, x1); x2 = fmaxf(x2, x3); x4 = fmaxf(x4, x5); x6 = fmaxf(x6, x7);
        x0 = fmaxf(x0, x2); x4 = fmaxf(x4, x6);
        float mx = fmaxf(x0, x4);
        mx = fmaxf(mx, __shfl_xor(mx, 32));
        float nm = fmaxf(m2, mx);
        if (__any(nm > m2)) {
            float scl = EXP2(m2 - nm);
            m2 = nm;
            lsum *= scl;
#pragma unroll
            for (int r = 0; r < 16; ++r) acc[r] *= scl;
        }
        float ps = 0.f;
#pragma unroll
        for (int r = 0; r < 16; ++r) {
            float p = EXP2(sc[r] - m2);
            sc[r] = p;
            ps += p;
        }
        ps += __shfl_xor(ps, 32);
        lsum += ps;

        // PV: acc[c][s] += g[c][t] * P[t][s]; P regs ARE the B-fragments
#pragma unroll
        for (int kk = 0; kk < 4; ++kk) {
            h4 bp;
            bp[0] = (_Float16)sc[4 * kk + 0];
            bp[1] = (_Float16)sc[4 * kk + 1];
            bp[2] = (_Float16)sc[4 * kk + 2];
            bp[3] = (_Float16)sc[4 * kk + 3];
            int t0 = tbase + 8 * kk + 4 * hi;
            int j = t0 >> 2;
            int js = (j & ~15) | ((j ^ ln) & 15);
            h4 ag = *(const h4*)&g_sh[ln * TT + js * 4];
            acc = MFMA328(ag, bp, acc);
        }
    }

    // ---- epilogue: out = gamma * (w_o . attn/l) + x, attn regs -> B-frags ----
    float linv = 1.f / lsum;
    h4 bat[4];
#pragma unroll
    for (int kk = 0; kk < 4; ++kk) {
        bat[kk][0] = (_Float16)(acc[4 * kk + 0] * linv);
        bat[kk][1] = (_Float16)(acc[4 * kk + 1] * linv);
        bat[kk][2] = (_Float16)(acc[4 * kk + 2] * linv);
        bat[kk][3] = (_Float16)(acc[4 * kk + 3] * linv);
    }
    float gm = gamma_p[0];
#pragma unroll
    for (int mt = 0; mt < 2; ++mt) {
        f32x16 d = MFMA328(a3[mt][0], bat[0], zero);
        d = MFMA328(a3[mt][1], bat[1], d);
        d = MFMA328(a3[mt][2], bat[2], d);
        d = MFMA328(a3[mt][3], bat[3], d);
#pragma unroll
        for (int r = 0; r < 16; ++r) {
            int ch = mt * 32 + (r & 3) + 8 * (r >> 2) + 4 * hi;
            size_t idx = (((size_t)(b * C + ch)) << 12) + sw + ln;
            out[idx] = gm * d[r] + x[idx];
        }
    }
}

// ---------------------------------------------------------------------------
extern "C" void kernel_launch(void* const* d_in, const int* in_sizes, int n_in,
                              void* d_out, int out_size, void* d_ws, size_t ws_size,
                              hipStream_t stream) {
    const float* x       = (const float*)d_in[0];
    const float* w_theta = (const float*)d_in[1];
    const float* w_phi   = (const float*)d_in[2];
    const float* w_g     = (const float*)d_in[3];
    const float* w_o     = (const float*)d_in[4];
    const float* gamma   = (const float*)d_in[5];
    float* out = (float*)d_out;

    _Float16* ws      = (_Float16*)d_ws;
    _Float16* theta_t = ws;                             // B*SS*8  halves
    _Float16* phi_t   = theta_t + (size_t)B * SS * 8;   // B*TT*8
    _Float16* g_blk   = phi_t + (size_t)B * TT * 8;     // B*TT*CG (blocked)

    k_proj<<<(B * SS) / 256, 256, 0, stream>>>(x, w_theta, w_phi, w_g,
                                               theta_t, phi_t, g_blk);
    k_attn<<<B * (SS / 128), 256, 0, stream>>>(x, theta_t, phi_t, g_blk,
                                               w_o, gamma, out);
}